// Round 1
// baseline (484.882 us; speedup 1.0000x reference)
//
#include <hip/hip_runtime.h>

#define NNODES 50000
#define NEDGES 600000
#define NGRAPHS 64
#define BN_EPS 1e-5f

// ---------------- graph-structure kernels ----------------

__global__ __launch_bounds__(256) void k_init(float* deg, int* cnt) {
    int i = blockIdx.x * 256 + threadIdx.x;
    if (i < NNODES) { deg[i] = 1.0f; cnt[i] = 0; }
}

__global__ __launch_bounds__(256) void k_edge_deg(const int* __restrict__ dst,
        const float* __restrict__ ew, float* __restrict__ deg, int* __restrict__ cnt) {
    int e = blockIdx.x * 256 + threadIdx.x;
    if (e < NEDGES) {
        int d = dst[e];
        atomicAdd(&deg[d], ew[e]);
        atomicAdd(&cnt[d], 1);
    }
}

__global__ __launch_bounds__(256) void k_dinv(float* deg) {
    int i = blockIdx.x * 256 + threadIdx.x;
    if (i < NNODES) { float v = deg[i]; deg[i] = (v > 0.f) ? rsqrtf(v) : 0.f; }
}

// single-block exclusive scan of cnt[0..NNODES) -> row_start, pos
__global__ void k_scan(const int* __restrict__ cnt, int* __restrict__ row_start,
                       int* __restrict__ pos) {
    __shared__ int sh[1024];
    int t = threadIdx.x;
    int run = 0;
    for (int base = 0; base < NNODES; base += 1024) {
        int idx = base + t;
        int v = (idx < NNODES) ? cnt[idx] : 0;
        sh[t] = v;
        __syncthreads();
        for (int off = 1; off < 1024; off <<= 1) {
            int x = (t >= off) ? sh[t - off] : 0;
            __syncthreads();
            sh[t] += x;
            __syncthreads();
        }
        int excl = sh[t] - v;
        if (idx < NNODES) { row_start[idx] = run + excl; pos[idx] = run + excl; }
        run += sh[1023];
        __syncthreads();
    }
    if (t == 0) row_start[NNODES] = run;
}

__global__ __launch_bounds__(256) void k_csr_fill(const int* __restrict__ src,
        const int* __restrict__ dst, const float* __restrict__ ew,
        const float* __restrict__ dinv, int* __restrict__ pos,
        int* __restrict__ csr_src, float* __restrict__ csr_w) {
    int e = blockIdx.x * 256 + threadIdx.x;
    if (e < NEDGES) {
        int s = src[e], d = dst[e];
        int slot = atomicAdd(&pos[d], 1);
        csr_src[slot] = s;
        csr_w[slot] = dinv[s] * ew[e] * dinv[d];
    }
}

// ---------------- fp32 GEMM: C[M,128] = A[M,128] @ W[128,128] ----------------
// 128x128 tile per block, 8x8 micro-tile per thread, k-chunks of 32.
// a_lds transposed [k][row] stride 132 (conflict-free b128 reads);
// w_lds col-swizzled: col c -> word 12*(c/8) + c%8 (2-way max on b128 reads).

__global__ __launch_bounds__(256) void k_gemm(const float* __restrict__ A,
        const float* __restrict__ W, float* __restrict__ C, int M) {
    __shared__ float a_lds[32][132];
    __shared__ float w_lds[32][192];
    const int tid = threadIdx.x;
    const int row0 = blockIdx.x * 128;
    const int tx = tid & 15;   // cols tx*8 .. tx*8+7
    const int ty = tid >> 4;   // rows ty*8 .. ty*8+7
    float acc[8][8];
#pragma unroll
    for (int i = 0; i < 8; ++i)
#pragma unroll
        for (int j = 0; j < 8; ++j) acc[i][j] = 0.f;

    for (int kc = 0; kc < 128; kc += 32) {
#pragma unroll
        for (int p = 0; p < 4; ++p) {            // stage A chunk (transposed)
            int idx = p * 256 + tid;
            int r = idx >> 3;
            int k4 = (idx & 7) << 2;
            int grow = row0 + r;
            float4 v = make_float4(0.f, 0.f, 0.f, 0.f);
            if (grow < M) v = *(const float4*)(A + (size_t)grow * 128 + kc + k4);
            a_lds[k4 + 0][r] = v.x; a_lds[k4 + 1][r] = v.y;
            a_lds[k4 + 2][r] = v.z; a_lds[k4 + 3][r] = v.w;
        }
#pragma unroll
        for (int p = 0; p < 4; ++p) {            // stage W chunk (swizzled)
            int idx = p * 256 + tid;
            int kk = idx >> 5;
            int c4 = idx & 31;
            float4 v = *(const float4*)(W + (size_t)(kc + kk) * 128 + c4 * 4);
            int sw = 12 * (c4 >> 1) + ((c4 & 1) << 2);
            *(float4*)&w_lds[kk][sw] = v;
        }
        __syncthreads();
#pragma unroll
        for (int k = 0; k < 32; ++k) {
            float a[8], b[8];
            *(float4*)&a[0] = *(const float4*)&a_lds[k][ty * 8];
            *(float4*)&a[4] = *(const float4*)&a_lds[k][ty * 8 + 4];
            *(float4*)&b[0] = *(const float4*)&w_lds[k][tx * 12];
            *(float4*)&b[4] = *(const float4*)&w_lds[k][tx * 12 + 4];
#pragma unroll
            for (int i = 0; i < 8; ++i)
#pragma unroll
                for (int j = 0; j < 8; ++j)
                    acc[i][j] = fmaf(a[i], b[j], acc[i][j]);
        }
        __syncthreads();
    }
#pragma unroll
    for (int i = 0; i < 8; ++i) {
        int grow = row0 + ty * 8 + i;
        if (grow < M) {
            float4 v0 = make_float4(acc[i][0], acc[i][1], acc[i][2], acc[i][3]);
            float4 v1 = make_float4(acc[i][4], acc[i][5], acc[i][6], acc[i][7]);
            *(float4*)(C + (size_t)grow * 128 + tx * 8) = v0;
            *(float4*)(C + (size_t)grow * 128 + tx * 8 + 4) = v1;
        }
    }
}

// ---------------- GCN aggregate: out = relu(A_hat @ h + bias) ----------------
// One wave (64 lanes) per node, float2 per lane (128 channels).

__global__ __launch_bounds__(256) void k_aggregate(const float* __restrict__ h,
        const float* __restrict__ dinv, const int* __restrict__ row_start,
        const int* __restrict__ csr_src, const float* __restrict__ csr_w,
        const float* __restrict__ bias, float* __restrict__ out) {
    int gtid = blockIdx.x * 256 + threadIdx.x;
    int i = gtid >> 6;
    int lane = gtid & 63;
    if (i >= NNODES) return;
    float di = dinv[i];
    float sw = di * di;
    float2 hv = *(const float2*)(h + (size_t)i * 128 + lane * 2);
    float ax = sw * hv.x, ay = sw * hv.y;
    int e1 = row_start[i + 1];
    for (int e = row_start[i]; e < e1; ++e) {
        int s = csr_src[e];
        float w = csr_w[e];
        float2 v = *(const float2*)(h + (size_t)s * 128 + lane * 2);
        ax = fmaf(w, v.x, ax);
        ay = fmaf(w, v.y, ay);
    }
    float2 b = *(const float2*)(bias + lane * 2);
    float2 o;
    o.x = fmaxf(ax + b.x, 0.f);
    o.y = fmaxf(ay + b.y, 0.f);
    *(float2*)(out + (size_t)i * 128 + lane * 2) = o;
}

// ---------------- pooling ----------------

__global__ void k_bounds(const int* __restrict__ batch, int* __restrict__ bnd) {
    int g = blockIdx.x * blockDim.x + threadIdx.x;
    if (g > NGRAPHS) return;
    int lo = 0, hi = NNODES;
    while (lo < hi) {
        int mid = (lo + hi) >> 1;
        if (batch[mid] < g) lo = mid + 1; else hi = mid;
    }
    bnd[g] = lo;
}

__global__ __launch_bounds__(512) void k_pool(const float* __restrict__ h2,
        const int* __restrict__ bnd, float* __restrict__ gmean) {
    __shared__ float sh[512];
    int g = blockIdx.x;
    int b0 = bnd[g], b1 = bnd[g + 1];
    int t = threadIdx.x;
    int c = t & 127, q = t >> 7;
    float acc = 0.f;
    for (int r = b0 + q; r < b1; r += 4) acc += h2[(size_t)r * 128 + c];
    sh[t] = acc;
    __syncthreads();
    if (t < 128) {
        float s = (sh[t] + sh[t + 128]) + (sh[t + 256] + sh[t + 384]);
        float n = (float)(b1 - b0);
        gmean[g * 128 + t] = s / fmaxf(n, 1.f);
    }
}

// ---------------- head: z = relu(g@fc1+b); BN(train-mode); out = z@fc3+b ----

__global__ __launch_bounds__(256) void k_head(const float* __restrict__ gmean,
        const float* __restrict__ fc1W, const float* __restrict__ fc1b,
        const float* __restrict__ gamma, const float* __restrict__ beta,
        const float* __restrict__ fc3W, const float* __restrict__ fc3b,
        float* __restrict__ out) {
    __shared__ float z[64][65];
    __shared__ float mu[64], isd[64];
    int t = threadIdx.x;
    int r = t >> 2;             // 0..63
    int c0 = (t & 3) * 16;      // 16 cols each
    float acc[16];
#pragma unroll
    for (int j = 0; j < 16; ++j) acc[j] = 0.f;
    for (int k = 0; k < 128; ++k) {
        float gv = gmean[r * 128 + k];
#pragma unroll
        for (int j = 0; j < 16; ++j) acc[j] = fmaf(gv, fc1W[k * 64 + c0 + j], acc[j]);
    }
#pragma unroll
    for (int j = 0; j < 16; ++j)
        z[r][c0 + j] = fmaxf(acc[j] + fc1b[c0 + j], 0.f);
    __syncthreads();
    if (t < 64) {
        float m = 0.f;
        for (int rr = 0; rr < 64; ++rr) m += z[rr][t];
        m *= (1.f / 64.f);
        float v = 0.f;
        for (int rr = 0; rr < 64; ++rr) { float d = z[rr][t] - m; v = fmaf(d, d, v); }
        v *= (1.f / 64.f);
        mu[t] = m;
        isd[t] = rsqrtf(v + BN_EPS);
    }
    __syncthreads();
    if (t < 64) {
        float a2 = fc3b[0];
        for (int cc = 0; cc < 64; ++cc) {
            float zn = fmaf(gamma[cc] * (z[t][cc] - mu[cc]), isd[cc], beta[cc]);
            a2 = fmaf(zn, fc3W[cc], a2);
        }
        out[t] = a2;
    }
}

// ---------------- launch ----------------

extern "C" void kernel_launch(void* const* d_in, const int* in_sizes, int n_in,
                              void* d_out, int out_size, void* d_ws, size_t ws_size,
                              hipStream_t stream) {
    const float* x    = (const float*)d_in[0];
    const int*   ei   = (const int*)d_in[1];
    const int*   batch= (const int*)d_in[2];
    const float* ew   = (const float*)d_in[3];
    const float* W1   = (const float*)d_in[4];
    const float* b1   = (const float*)d_in[5];
    const float* W2   = (const float*)d_in[6];
    const float* b2   = (const float*)d_in[7];
    const float* fc1W = (const float*)d_in[8];
    const float* fc1b = (const float*)d_in[9];
    const float* gam  = (const float*)d_in[10];
    const float* bet  = (const float*)d_in[11];
    const float* fc3W = (const float*)d_in[12];
    const float* fc3b = (const float*)d_in[13];
    float* out = (float*)d_out;
    const int* srcp = ei;
    const int* dstp = ei + NEDGES;

    char* wsb = (char*)d_ws;
    size_t off = 0;
    auto alloc = [&](size_t bytes) {
        void* p = wsb + off;
        off = (off + bytes + 255) & ~(size_t)255;
        return p;
    };
    float* dinv      = (float*)alloc(NNODES * 4);
    int*   row_start = (int*)alloc((NNODES + 1) * 4);
    int*   pos       = (int*)alloc(NNODES * 4);
    int*   cnt       = (int*)alloc(NNODES * 4);
    int*   csr_src   = (int*)alloc(NEDGES * 4);
    float* csr_w     = (float*)alloc(NEDGES * 4);
    float* hbuf      = (float*)alloc((size_t)NNODES * 128 * 4);
    float* abuf      = (float*)alloc((size_t)NNODES * 128 * 4);
    int*   bnd       = (int*)alloc((NGRAPHS + 1) * 4);
    float* gmean     = (float*)alloc(NGRAPHS * 128 * 4);
    (void)ws_size; (void)in_sizes; (void)n_in; (void)out_size;

    const int nb_nodes = (NNODES + 255) / 256;
    const int nb_edges = (NEDGES + 255) / 256;

    k_init<<<nb_nodes, 256, 0, stream>>>(dinv, cnt);
    k_edge_deg<<<nb_edges, 256, 0, stream>>>(dstp, ew, dinv, cnt);
    k_dinv<<<nb_nodes, 256, 0, stream>>>(dinv);
    k_scan<<<1, 1024, 0, stream>>>(cnt, row_start, pos);
    k_csr_fill<<<nb_edges, 256, 0, stream>>>(srcp, dstp, ew, dinv, pos, csr_src, csr_w);

    // layer 1
    k_gemm<<<(NNODES + 127) / 128, 256, 0, stream>>>(x, W1, hbuf, NNODES);
    k_aggregate<<<(NNODES * 64 + 255) / 256, 256, 0, stream>>>(hbuf, dinv, row_start,
                                                               csr_src, csr_w, b1, abuf);
    // layer 2
    k_gemm<<<(NNODES + 127) / 128, 256, 0, stream>>>(abuf, W2, hbuf, NNODES);
    k_aggregate<<<(NNODES * 64 + 255) / 256, 256, 0, stream>>>(hbuf, dinv, row_start,
                                                               csr_src, csr_w, b2, abuf);
    // pool + head
    k_bounds<<<1, 128, 0, stream>>>(batch, bnd);
    k_pool<<<NGRAPHS, 512, 0, stream>>>(abuf, bnd, gmean);
    k_head<<<1, 256, 0, stream>>>(gmean, fc1W, fc1b, gam, bet, fc3W, fc3b, out);
}

// Round 2
// 361.304 us; speedup vs baseline: 1.3420x; 1.3420x over previous
//
#include <hip/hip_runtime.h>

#define NNODES 50000
#define NEDGES 600000
#define NGRAPHS 64
#define BN_EPS 1e-5f
#define NB1 ((NNODES + 255) / 256)   // 196 scan blocks

// ---------------- graph-structure kernels ----------------

__global__ __launch_bounds__(256) void k_init(float* deg, int* cnt) {
    int i = blockIdx.x * 256 + threadIdx.x;
    if (i < NNODES) { deg[i] = 1.0f; cnt[i] = 0; }
}

__global__ __launch_bounds__(256) void k_edge_deg(const int* __restrict__ dst,
        const float* __restrict__ ew, float* __restrict__ deg, int* __restrict__ cnt) {
    int e = blockIdx.x * 256 + threadIdx.x;
    if (e < NEDGES) {
        int d = dst[e];
        atomicAdd(&deg[d], ew[e]);
        atomicAdd(&cnt[d], 1);
    }
}

// scan phase 1: per-256-block exclusive scan + block sum; fused deg -> dinv
__global__ __launch_bounds__(256) void k_scan1(const int* __restrict__ cnt,
        int* __restrict__ excl, int* __restrict__ bsum, float* __restrict__ deg) {
    __shared__ int sh[256];
    int b = blockIdx.x, t = threadIdx.x;
    int idx = b * 256 + t;
    int v = (idx < NNODES) ? cnt[idx] : 0;
    sh[t] = v;
    if (idx < NNODES) { float d = deg[idx]; deg[idx] = (d > 0.f) ? rsqrtf(d) : 0.f; }
    __syncthreads();
#pragma unroll
    for (int off = 1; off < 256; off <<= 1) {
        int x = (t >= off) ? sh[t - off] : 0;
        __syncthreads();
        sh[t] += x;
        __syncthreads();
    }
    if (idx < NNODES) excl[idx] = sh[t] - v;
    if (t == 255) bsum[b] = sh[255];
}

// scan phase 2: single block exclusive-scans the NB1 block sums in place
__global__ __launch_bounds__(256) void k_scan2(int* __restrict__ bsum) {
    __shared__ int sh[256];
    int t = threadIdx.x;
    int v = (t < NB1) ? bsum[t] : 0;
    sh[t] = v;
    __syncthreads();
#pragma unroll
    for (int off = 1; off < 256; off <<= 1) {
        int x = (t >= off) ? sh[t - off] : 0;
        __syncthreads();
        sh[t] += x;
        __syncthreads();
    }
    if (t < NB1) bsum[t] = sh[t] - v;
}

// scan phase 3: add block offsets -> row_start, pos
__global__ __launch_bounds__(256) void k_scan3(const int* __restrict__ excl,
        const int* __restrict__ bsum, int* __restrict__ row_start, int* __restrict__ pos) {
    int b = blockIdx.x, t = threadIdx.x;
    int idx = b * 256 + t;
    if (idx < NNODES) {
        int v = excl[idx] + bsum[b];
        row_start[idx] = v;
        pos[idx] = v;
    }
    if (idx == 0) row_start[NNODES] = NEDGES;  // total degree is statically known
}

__global__ __launch_bounds__(256) void k_csr_fill(const int* __restrict__ src,
        const int* __restrict__ dst, const float* __restrict__ ew,
        const float* __restrict__ dinv, int* __restrict__ pos,
        int* __restrict__ csr_src, float* __restrict__ csr_w) {
    int e = blockIdx.x * 256 + threadIdx.x;
    if (e < NEDGES) {
        int s = src[e], d = dst[e];
        int slot = atomicAdd(&pos[d], 1);
        csr_src[slot] = s;
        csr_w[slot] = dinv[s] * ew[e] * dinv[d];
    }
}

// ---------------- fp32 GEMM: C[M,128] = A[M,128] @ W[128,128] ----------------

__global__ __launch_bounds__(256) void k_gemm(const float* __restrict__ A,
        const float* __restrict__ W, float* __restrict__ C, int M) {
    __shared__ float a_lds[32][132];
    __shared__ float w_lds[32][192];
    const int tid = threadIdx.x;
    const int row0 = blockIdx.x * 128;
    const int tx = tid & 15;
    const int ty = tid >> 4;
    float acc[8][8];
#pragma unroll
    for (int i = 0; i < 8; ++i)
#pragma unroll
        for (int j = 0; j < 8; ++j) acc[i][j] = 0.f;

    for (int kc = 0; kc < 128; kc += 32) {
#pragma unroll
        for (int p = 0; p < 4; ++p) {
            int idx = p * 256 + tid;
            int r = idx >> 3;
            int k4 = (idx & 7) << 2;
            int grow = row0 + r;
            float4 v = make_float4(0.f, 0.f, 0.f, 0.f);
            if (grow < M) v = *(const float4*)(A + (size_t)grow * 128 + kc + k4);
            a_lds[k4 + 0][r] = v.x; a_lds[k4 + 1][r] = v.y;
            a_lds[k4 + 2][r] = v.z; a_lds[k4 + 3][r] = v.w;
        }
#pragma unroll
        for (int p = 0; p < 4; ++p) {
            int idx = p * 256 + tid;
            int kk = idx >> 5;
            int c4 = idx & 31;
            float4 v = *(const float4*)(W + (size_t)(kc + kk) * 128 + c4 * 4);
            int sw = 12 * (c4 >> 1) + ((c4 & 1) << 2);
            *(float4*)&w_lds[kk][sw] = v;
        }
        __syncthreads();
#pragma unroll
        for (int k = 0; k < 32; ++k) {
            float a[8], b[8];
            *(float4*)&a[0] = *(const float4*)&a_lds[k][ty * 8];
            *(float4*)&a[4] = *(const float4*)&a_lds[k][ty * 8 + 4];
            *(float4*)&b[0] = *(const float4*)&w_lds[k][tx * 12];
            *(float4*)&b[4] = *(const float4*)&w_lds[k][tx * 12 + 4];
#pragma unroll
            for (int i = 0; i < 8; ++i)
#pragma unroll
                for (int j = 0; j < 8; ++j)
                    acc[i][j] = fmaf(a[i], b[j], acc[i][j]);
        }
        __syncthreads();
    }
#pragma unroll
    for (int i = 0; i < 8; ++i) {
        int grow = row0 + ty * 8 + i;
        if (grow < M) {
            float4 v0 = make_float4(acc[i][0], acc[i][1], acc[i][2], acc[i][3]);
            float4 v1 = make_float4(acc[i][4], acc[i][5], acc[i][6], acc[i][7]);
            *(float4*)(C + (size_t)grow * 128 + tx * 8) = v0;
            *(float4*)(C + (size_t)grow * 128 + tx * 8 + 4) = v1;
        }
    }
}

// ---------------- GCN aggregate: out = relu(A_hat @ h + bias) ----------------
// 32 lanes per node, float4 per lane (128 ch); 2-edge unrolled gather.

__global__ __launch_bounds__(256) void k_aggregate(const float* __restrict__ h,
        const float* __restrict__ dinv, const int* __restrict__ row_start,
        const int* __restrict__ csr_src, const float* __restrict__ csr_w,
        const float* __restrict__ bias, float* __restrict__ out) {
    int gtid = blockIdx.x * 256 + threadIdx.x;
    int i = gtid >> 5;
    int lane = (gtid & 31) << 2;
    if (i >= NNODES) return;
    float di = dinv[i];
    float sw = di * di;
    float4 hv = *(const float4*)(h + (size_t)i * 128 + lane);
    float ax = sw * hv.x, ay = sw * hv.y, az = sw * hv.z, aw = sw * hv.w;
    int e = row_start[i];
    int e1 = row_start[i + 1];
    for (; e + 1 < e1; e += 2) {
        int s0 = csr_src[e], s1 = csr_src[e + 1];
        float w0 = csr_w[e], w1 = csr_w[e + 1];
        float4 v0 = *(const float4*)(h + (size_t)s0 * 128 + lane);
        float4 v1 = *(const float4*)(h + (size_t)s1 * 128 + lane);
        ax = fmaf(w0, v0.x, ax); ay = fmaf(w0, v0.y, ay);
        az = fmaf(w0, v0.z, az); aw = fmaf(w0, v0.w, aw);
        ax = fmaf(w1, v1.x, ax); ay = fmaf(w1, v1.y, ay);
        az = fmaf(w1, v1.z, az); aw = fmaf(w1, v1.w, aw);
    }
    if (e < e1) {
        int s0 = csr_src[e];
        float w0 = csr_w[e];
        float4 v0 = *(const float4*)(h + (size_t)s0 * 128 + lane);
        ax = fmaf(w0, v0.x, ax); ay = fmaf(w0, v0.y, ay);
        az = fmaf(w0, v0.z, az); aw = fmaf(w0, v0.w, aw);
    }
    float4 b = *(const float4*)(bias + lane);
    float4 o;
    o.x = fmaxf(ax + b.x, 0.f);
    o.y = fmaxf(ay + b.y, 0.f);
    o.z = fmaxf(az + b.z, 0.f);
    o.w = fmaxf(aw + b.w, 0.f);
    *(float4*)(out + (size_t)i * 128 + lane) = o;
}

// ---------------- pooling (graph bounds fused via binary search) ----------------

__global__ __launch_bounds__(512) void k_pool(const float* __restrict__ h2,
        const int* __restrict__ batch, float* __restrict__ gmean) {
    __shared__ float sh[512];
    int g = blockIdx.x;
    int t = threadIdx.x;
    // every thread finds [b0,b1) for graph g via binary search (redundant, cheap)
    int lo = 0, hi = NNODES;
    while (lo < hi) { int mid = (lo + hi) >> 1; if (batch[mid] < g) lo = mid + 1; else hi = mid; }
    int b0 = lo;
    lo = 0; hi = NNODES;
    int g1 = g + 1;
    while (lo < hi) { int mid = (lo + hi) >> 1; if (batch[mid] < g1) lo = mid + 1; else hi = mid; }
    int b1 = lo;

    int c = t & 127, q = t >> 7;
    float acc = 0.f;
    for (int r = b0 + q; r < b1; r += 4) acc += h2[(size_t)r * 128 + c];
    sh[t] = acc;
    __syncthreads();
    if (t < 128) {
        float s = (sh[t] + sh[t + 128]) + (sh[t + 256] + sh[t + 384]);
        float n = (float)(b1 - b0);
        gmean[g * 128 + t] = s / fmaxf(n, 1.f);
    }
}

// ---------------- head: z = relu(g@fc1+b); BN(train-mode); out = z@fc3+b ----

__global__ __launch_bounds__(256) void k_head(const float* __restrict__ gmean,
        const float* __restrict__ fc1W, const float* __restrict__ fc1b,
        const float* __restrict__ gamma, const float* __restrict__ beta,
        const float* __restrict__ fc3W, const float* __restrict__ fc3b,
        float* __restrict__ out) {
    __shared__ float z[64][65];
    __shared__ float mu[64], isd[64];
    int t = threadIdx.x;
    int r = t >> 2;
    int c0 = (t & 3) * 16;
    float acc[16];
#pragma unroll
    for (int j = 0; j < 16; ++j) acc[j] = 0.f;
    for (int k = 0; k < 128; ++k) {
        float gv = gmean[r * 128 + k];
#pragma unroll
        for (int j = 0; j < 16; ++j) acc[j] = fmaf(gv, fc1W[k * 64 + c0 + j], acc[j]);
    }
#pragma unroll
    for (int j = 0; j < 16; ++j)
        z[r][c0 + j] = fmaxf(acc[j] + fc1b[c0 + j], 0.f);
    __syncthreads();
    if (t < 64) {
        float m = 0.f;
        for (int rr = 0; rr < 64; ++rr) m += z[rr][t];
        m *= (1.f / 64.f);
        float v = 0.f;
        for (int rr = 0; rr < 64; ++rr) { float d = z[rr][t] - m; v = fmaf(d, d, v); }
        v *= (1.f / 64.f);
        mu[t] = m;
        isd[t] = rsqrtf(v + BN_EPS);
    }
    __syncthreads();
    if (t < 64) {
        float a2 = fc3b[0];
        for (int cc = 0; cc < 64; ++cc) {
            float zn = fmaf(gamma[cc] * (z[t][cc] - mu[cc]), isd[cc], beta[cc]);
            a2 = fmaf(zn, fc3W[cc], a2);
        }
        out[t] = a2;
    }
}

// ---------------- launch ----------------

extern "C" void kernel_launch(void* const* d_in, const int* in_sizes, int n_in,
                              void* d_out, int out_size, void* d_ws, size_t ws_size,
                              hipStream_t stream) {
    const float* x    = (const float*)d_in[0];
    const int*   ei   = (const int*)d_in[1];
    const int*   batch= (const int*)d_in[2];
    const float* ew   = (const float*)d_in[3];
    const float* W1   = (const float*)d_in[4];
    const float* b1   = (const float*)d_in[5];
    const float* W2   = (const float*)d_in[6];
    const float* b2   = (const float*)d_in[7];
    const float* fc1W = (const float*)d_in[8];
    const float* fc1b = (const float*)d_in[9];
    const float* gam  = (const float*)d_in[10];
    const float* bet  = (const float*)d_in[11];
    const float* fc3W = (const float*)d_in[12];
    const float* fc3b = (const float*)d_in[13];
    float* out = (float*)d_out;
    const int* srcp = ei;
    const int* dstp = ei + NEDGES;

    char* wsb = (char*)d_ws;
    size_t off = 0;
    auto alloc = [&](size_t bytes) {
        void* p = wsb + off;
        off = (off + bytes + 255) & ~(size_t)255;
        return p;
    };
    float* dinv      = (float*)alloc(NNODES * 4);
    int*   row_start = (int*)alloc((NNODES + 1) * 4);
    int*   pos       = (int*)alloc(NNODES * 4);
    int*   cnt       = (int*)alloc(NNODES * 4);
    int*   excl      = (int*)alloc(NNODES * 4);
    int*   bsum      = (int*)alloc(NB1 * 4);
    int*   csr_src   = (int*)alloc(NEDGES * 4);
    float* csr_w     = (float*)alloc(NEDGES * 4);
    float* hbuf      = (float*)alloc((size_t)NNODES * 128 * 4);
    float* abuf      = (float*)alloc((size_t)NNODES * 128 * 4);
    float* gmean     = (float*)alloc(NGRAPHS * 128 * 4);
    (void)ws_size; (void)in_sizes; (void)n_in; (void)out_size;

    const int nb_nodes = NB1;
    const int nb_edges = (NEDGES + 255) / 256;

    k_init<<<nb_nodes, 256, 0, stream>>>(dinv, cnt);
    k_edge_deg<<<nb_edges, 256, 0, stream>>>(dstp, ew, dinv, cnt);
    k_scan1<<<nb_nodes, 256, 0, stream>>>(cnt, excl, bsum, dinv);
    k_scan2<<<1, 256, 0, stream>>>(bsum);
    k_scan3<<<nb_nodes, 256, 0, stream>>>(excl, bsum, row_start, pos);
    k_csr_fill<<<nb_edges, 256, 0, stream>>>(srcp, dstp, ew, dinv, pos, csr_src, csr_w);

    // layer 1
    k_gemm<<<(NNODES + 127) / 128, 256, 0, stream>>>(x, W1, hbuf, NNODES);
    k_aggregate<<<(NNODES * 32 + 255) / 256, 256, 0, stream>>>(hbuf, dinv, row_start,
                                                               csr_src, csr_w, b1, abuf);
    // layer 2
    k_gemm<<<(NNODES + 127) / 128, 256, 0, stream>>>(abuf, W2, hbuf, NNODES);
    k_aggregate<<<(NNODES * 32 + 255) / 256, 256, 0, stream>>>(hbuf, dinv, row_start,
                                                               csr_src, csr_w, b2, abuf);
    // pool + head
    k_pool<<<NGRAPHS, 512, 0, stream>>>(abuf, batch, gmean);
    k_head<<<1, 256, 0, stream>>>(gmean, fc1W, fc1b, gam, bet, fc3W, fc3b, out);
}

// Round 4
// 324.124 us; speedup vs baseline: 1.4960x; 1.1147x over previous
//
#include <hip/hip_runtime.h>

#define NNODES 50000
#define NEDGES 600000
#define NGRAPHS 64
#define BN_EPS 1e-5f
#define NB1 ((NNODES + 255) / 256)   // 196 scan blocks
#define PPG 16                        // pooling parts per graph

// ---------------- graph-structure kernels ----------------

__global__ __launch_bounds__(256) void k_init(float* deg, int* cnt) {
    int i = blockIdx.x * 256 + threadIdx.x;
    if (i < NNODES) { deg[i] = 1.0f; cnt[i] = 0; }
}

__global__ __launch_bounds__(256) void k_edge_deg(const int* __restrict__ dst,
        const float* __restrict__ ew, float* __restrict__ deg, int* __restrict__ cnt) {
    int e = blockIdx.x * 256 + threadIdx.x;
    if (e < NEDGES) {
        int d = dst[e];
        atomicAdd(&deg[d], ew[e]);
        atomicAdd(&cnt[d], 1);
    }
}

// scan phase 1: per-256-block exclusive scan + block sum; fused deg -> dinv
__global__ __launch_bounds__(256) void k_scan1(const int* __restrict__ cnt,
        int* __restrict__ excl, int* __restrict__ bsum, float* __restrict__ deg) {
    __shared__ int sh[256];
    int b = blockIdx.x, t = threadIdx.x;
    int idx = b * 256 + t;
    int v = (idx < NNODES) ? cnt[idx] : 0;
    sh[t] = v;
    if (idx < NNODES) { float d = deg[idx]; deg[idx] = (d > 0.f) ? rsqrtf(d) : 0.f; }
    __syncthreads();
#pragma unroll
    for (int off = 1; off < 256; off <<= 1) {
        int x = (t >= off) ? sh[t - off] : 0;
        __syncthreads();
        sh[t] += x;
        __syncthreads();
    }
    if (idx < NNODES) excl[idx] = sh[t] - v;
    if (t == 255) bsum[b] = sh[255];
}

__global__ __launch_bounds__(256) void k_scan2(int* __restrict__ bsum) {
    __shared__ int sh[256];
    int t = threadIdx.x;
    int v = (t < NB1) ? bsum[t] : 0;
    sh[t] = v;
    __syncthreads();
#pragma unroll
    for (int off = 1; off < 256; off <<= 1) {
        int x = (t >= off) ? sh[t - off] : 0;
        __syncthreads();
        sh[t] += x;
        __syncthreads();
    }
    if (t < NB1) bsum[t] = sh[t] - v;
}

__global__ __launch_bounds__(256) void k_scan3(const int* __restrict__ excl,
        const int* __restrict__ bsum, int* __restrict__ row_start, int* __restrict__ pos) {
    int b = blockIdx.x, t = threadIdx.x;
    int idx = b * 256 + t;
    if (idx < NNODES) {
        int v = excl[idx] + bsum[b];
        row_start[idx] = v;
        pos[idx] = v;
    }
    if (idx == 0) row_start[NNODES] = NEDGES;
}

__global__ __launch_bounds__(256) void k_csr_fill(const int* __restrict__ src,
        const int* __restrict__ dst, const float* __restrict__ ew,
        const float* __restrict__ dinv, int* __restrict__ pos,
        int* __restrict__ csr_src, float* __restrict__ csr_w) {
    int e = blockIdx.x * 256 + threadIdx.x;
    if (e < NEDGES) {
        int s = src[e], d = dst[e];
        int slot = atomicAdd(&pos[d], 1);
        csr_src[slot] = s;
        csr_w[slot] = dinv[s] * ew[e] * dinv[d];
    }
}

// ---------------- fp32 GEMM: C[M,128] = A[M,128] @ W[128,128] ----------------

__global__ __launch_bounds__(256) void k_gemm(const float* __restrict__ A,
        const float* __restrict__ W, float* __restrict__ C, int M) {
    __shared__ float a_lds[32][132];
    __shared__ float w_lds[32][192];
    const int tid = threadIdx.x;
    const int row0 = blockIdx.x * 128;
    const int tx = tid & 15;
    const int ty = tid >> 4;
    float acc[8][8];
#pragma unroll
    for (int i = 0; i < 8; ++i)
#pragma unroll
        for (int j = 0; j < 8; ++j) acc[i][j] = 0.f;

    for (int kc = 0; kc < 128; kc += 32) {
#pragma unroll
        for (int p = 0; p < 4; ++p) {
            int idx = p * 256 + tid;
            int r = idx >> 3;
            int k4 = (idx & 7) << 2;
            int grow = row0 + r;
            float4 v = make_float4(0.f, 0.f, 0.f, 0.f);
            if (grow < M) v = *(const float4*)(A + (size_t)grow * 128 + kc + k4);
            a_lds[k4 + 0][r] = v.x; a_lds[k4 + 1][r] = v.y;
            a_lds[k4 + 2][r] = v.z; a_lds[k4 + 3][r] = v.w;
        }
#pragma unroll
        for (int p = 0; p < 4; ++p) {
            int idx = p * 256 + tid;
            int kk = idx >> 5;
            int c4 = idx & 31;
            float4 v = *(const float4*)(W + (size_t)(kc + kk) * 128 + c4 * 4);
            int sw = 12 * (c4 >> 1) + ((c4 & 1) << 2);
            *(float4*)&w_lds[kk][sw] = v;
        }
        __syncthreads();
#pragma unroll
        for (int k = 0; k < 32; ++k) {
            float a[8], b[8];
            *(float4*)&a[0] = *(const float4*)&a_lds[k][ty * 8];
            *(float4*)&a[4] = *(const float4*)&a_lds[k][ty * 8 + 4];
            *(float4*)&b[0] = *(const float4*)&w_lds[k][tx * 12];
            *(float4*)&b[4] = *(const float4*)&w_lds[k][tx * 12 + 4];
#pragma unroll
            for (int i = 0; i < 8; ++i)
#pragma unroll
                for (int j = 0; j < 8; ++j)
                    acc[i][j] = fmaf(a[i], b[j], acc[i][j]);
        }
        __syncthreads();
    }
#pragma unroll
    for (int i = 0; i < 8; ++i) {
        int grow = row0 + ty * 8 + i;
        if (grow < M) {
            float4 v0 = make_float4(acc[i][0], acc[i][1], acc[i][2], acc[i][3]);
            float4 v1 = make_float4(acc[i][4], acc[i][5], acc[i][6], acc[i][7]);
            *(float4*)(C + (size_t)grow * 128 + tx * 8) = v0;
            *(float4*)(C + (size_t)grow * 128 + tx * 8 + 4) = v1;
        }
    }
}

// ---------------- GCN aggregate: out = relu(A_hat @ h + bias) ----------------
// 32 lanes per node, float4 per lane (128 ch); 4-edge unrolled gather.

__global__ __launch_bounds__(256) void k_aggregate(const float* __restrict__ h,
        const float* __restrict__ dinv, const int* __restrict__ row_start,
        const int* __restrict__ csr_src, const float* __restrict__ csr_w,
        const float* __restrict__ bias, float* __restrict__ out) {
    int gtid = blockIdx.x * 256 + threadIdx.x;
    int i = gtid >> 5;
    int lane = (gtid & 31) << 2;
    if (i >= NNODES) return;
    float di = dinv[i];
    float sw = di * di;
    float4 hv = *(const float4*)(h + (size_t)i * 128 + lane);
    float ax = sw * hv.x, ay = sw * hv.y, az = sw * hv.z, aw = sw * hv.w;
    int e = row_start[i];
    int e1 = row_start[i + 1];
    for (; e + 3 < e1; e += 4) {
        int s0 = csr_src[e], s1 = csr_src[e + 1], s2 = csr_src[e + 2], s3 = csr_src[e + 3];
        float w0 = csr_w[e], w1 = csr_w[e + 1], w2 = csr_w[e + 2], w3 = csr_w[e + 3];
        float4 v0 = *(const float4*)(h + (size_t)s0 * 128 + lane);
        float4 v1 = *(const float4*)(h + (size_t)s1 * 128 + lane);
        float4 v2 = *(const float4*)(h + (size_t)s2 * 128 + lane);
        float4 v3 = *(const float4*)(h + (size_t)s3 * 128 + lane);
        ax = fmaf(w0, v0.x, ax); ay = fmaf(w0, v0.y, ay);
        az = fmaf(w0, v0.z, az); aw = fmaf(w0, v0.w, aw);
        ax = fmaf(w1, v1.x, ax); ay = fmaf(w1, v1.y, ay);
        az = fmaf(w1, v1.z, az); aw = fmaf(w1, v1.w, aw);
        ax = fmaf(w2, v2.x, ax); ay = fmaf(w2, v2.y, ay);
        az = fmaf(w2, v2.z, az); aw = fmaf(w2, v2.w, aw);
        ax = fmaf(w3, v3.x, ax); ay = fmaf(w3, v3.y, ay);
        az = fmaf(w3, v3.z, az); aw = fmaf(w3, v3.w, aw);
    }
    for (; e < e1; ++e) {
        int s0 = csr_src[e];
        float w0 = csr_w[e];
        float4 v0 = *(const float4*)(h + (size_t)s0 * 128 + lane);
        ax = fmaf(w0, v0.x, ax); ay = fmaf(w0, v0.y, ay);
        az = fmaf(w0, v0.z, az); aw = fmaf(w0, v0.w, aw);
    }
    float4 b = *(const float4*)(bias + lane);
    float4 o;
    o.x = fmaxf(ax + b.x, 0.f);
    o.y = fmaxf(ay + b.y, 0.f);
    o.z = fmaxf(az + b.z, 0.f);
    o.w = fmaxf(aw + b.w, 0.f);
    *(float4*)(out + (size_t)i * 128 + lane) = o;
}

// ---------------- pooling: 2-phase deterministic partial sums ----------------
// phase 1: PPG blocks per graph, each sums a fixed strided row subset.

__global__ __launch_bounds__(256) void k_pool1(const float* __restrict__ h2,
        const int* __restrict__ batch, float* __restrict__ part) {
    __shared__ float sh[256];
    int g = blockIdx.x / PPG;
    int p = blockIdx.x % PPG;
    int t = threadIdx.x;
    int lo = 0, hi = NNODES;
    while (lo < hi) { int mid = (lo + hi) >> 1; if (batch[mid] < g) lo = mid + 1; else hi = mid; }
    int b0 = lo;
    lo = 0; hi = NNODES;
    int g1 = g + 1;
    while (lo < hi) { int mid = (lo + hi) >> 1; if (batch[mid] < g1) lo = mid + 1; else hi = mid; }
    int b1 = lo;

    int c = t & 127, q = t >> 7;   // 128 cols x 2 row-streams
    float acc = 0.f;
    for (int r = b0 + p * 2 + q; r < b1; r += PPG * 2) acc += h2[(size_t)r * 128 + c];
    sh[t] = acc;
    __syncthreads();
    if (t < 128) part[((size_t)g * PPG + p) * 128 + t] = sh[t] + sh[t + 128];
}

// phase 2: reduce PPG partials, divide by graph size.
__global__ __launch_bounds__(128) void k_pool2(const float* __restrict__ part,
        const int* __restrict__ batch, float* __restrict__ gmean) {
    int g = blockIdx.x;
    int t = threadIdx.x;
    int lo = 0, hi = NNODES;
    while (lo < hi) { int mid = (lo + hi) >> 1; if (batch[mid] < g) lo = mid + 1; else hi = mid; }
    int b0 = lo;
    lo = 0; hi = NNODES;
    int g1 = g + 1;
    while (lo < hi) { int mid = (lo + hi) >> 1; if (batch[mid] < g1) lo = mid + 1; else hi = mid; }
    int b1 = lo;
    float s = 0.f;
#pragma unroll
    for (int p = 0; p < PPG; ++p) s += part[((size_t)g * PPG + p) * 128 + t];
    float n = (float)(b1 - b0);
    gmean[g * 128 + t] = s / fmaxf(n, 1.f);
}

// ---------------- head: z = relu(g@fc1+b); BN(train-mode); out = z@fc3+b ----

__global__ __launch_bounds__(256) void k_head(const float* __restrict__ gmean,
        const float* __restrict__ fc1W, const float* __restrict__ fc1b,
        const float* __restrict__ gamma, const float* __restrict__ beta,
        const float* __restrict__ fc3W, const float* __restrict__ fc3b,
        float* __restrict__ out) {
    __shared__ float z[64][65];
    __shared__ float mu[64], isd[64];
    int t = threadIdx.x;
    int r = t >> 2;
    int c0 = (t & 3) * 16;
    float acc[16];
#pragma unroll
    for (int j = 0; j < 16; ++j) acc[j] = 0.f;
    for (int k = 0; k < 128; ++k) {
        float gv = gmean[r * 128 + k];
#pragma unroll
        for (int j = 0; j < 16; ++j) acc[j] = fmaf(gv, fc1W[k * 64 + c0 + j], acc[j]);
    }
#pragma unroll
    for (int j = 0; j < 16; ++j)
        z[r][c0 + j] = fmaxf(acc[j] + fc1b[c0 + j], 0.f);
    __syncthreads();
    if (t < 64) {
        float m = 0.f;
        for (int rr = 0; rr < 64; ++rr) m += z[rr][t];
        m *= (1.f / 64.f);
        float v = 0.f;
        for (int rr = 0; rr < 64; ++rr) { float d = z[rr][t] - m; v = fmaf(d, d, v); }
        v *= (1.f / 64.f);
        mu[t] = m;
        isd[t] = rsqrtf(v + BN_EPS);
    }
    __syncthreads();
    if (t < 64) {
        float a2 = fc3b[0];
        for (int cc = 0; cc < 64; ++cc) {
            float zn = fmaf(gamma[cc] * (z[t][cc] - mu[cc]), isd[cc], beta[cc]);
            a2 = fmaf(zn, fc3W[cc], a2);
        }
        out[t] = a2;
    }
}

// ---------------- launch ----------------

extern "C" void kernel_launch(void* const* d_in, const int* in_sizes, int n_in,
                              void* d_out, int out_size, void* d_ws, size_t ws_size,
                              hipStream_t stream) {
    const float* x    = (const float*)d_in[0];
    const int*   ei   = (const int*)d_in[1];
    const int*   batch= (const int*)d_in[2];
    const float* ew   = (const float*)d_in[3];
    const float* W1   = (const float*)d_in[4];
    const float* b1   = (const float*)d_in[5];
    const float* W2   = (const float*)d_in[6];
    const float* b2   = (const float*)d_in[7];
    const float* fc1W = (const float*)d_in[8];
    const float* fc1b = (const float*)d_in[9];
    const float* gam  = (const float*)d_in[10];
    const float* bet  = (const float*)d_in[11];
    const float* fc3W = (const float*)d_in[12];
    const float* fc3b = (const float*)d_in[13];
    float* out = (float*)d_out;
    const int* srcp = ei;
    const int* dstp = ei + NEDGES;

    char* wsb = (char*)d_ws;
    size_t off = 0;
    auto alloc = [&](size_t bytes) {
        void* p = wsb + off;
        off = (off + bytes + 255) & ~(size_t)255;
        return p;
    };
    float* dinv      = (float*)alloc(NNODES * 4);
    int*   row_start = (int*)alloc((NNODES + 1) * 4);
    int*   pos       = (int*)alloc(NNODES * 4);
    int*   cnt       = (int*)alloc(NNODES * 4);
    int*   excl      = (int*)alloc(NNODES * 4);
    int*   bsum      = (int*)alloc(NB1 * 4);
    int*   csr_src   = (int*)alloc(NEDGES * 4);
    float* csr_w     = (float*)alloc(NEDGES * 4);
    float* hbuf      = (float*)alloc((size_t)NNODES * 128 * 4);
    float* abuf      = (float*)alloc((size_t)NNODES * 128 * 4);
    float* part      = (float*)alloc((size_t)NGRAPHS * PPG * 128 * 4);
    float* gmean     = (float*)alloc(NGRAPHS * 128 * 4);
    (void)ws_size; (void)in_sizes; (void)n_in; (void)out_size;

    const int nb_nodes = NB1;
    const int nb_edges = (NEDGES + 255) / 256;

    k_init<<<nb_nodes, 256, 0, stream>>>(dinv, cnt);
    k_edge_deg<<<nb_edges, 256, 0, stream>>>(dstp, ew, dinv, cnt);
    k_scan1<<<nb_nodes, 256, 0, stream>>>(cnt, excl, bsum, dinv);
    k_scan2<<<1, 256, 0, stream>>>(bsum);
    k_scan3<<<nb_nodes, 256, 0, stream>>>(excl, bsum, row_start, pos);
    k_csr_fill<<<nb_edges, 256, 0, stream>>>(srcp, dstp, ew, dinv, pos, csr_src, csr_w);

    // layer 1
    k_gemm<<<(NNODES + 127) / 128, 256, 0, stream>>>(x, W1, hbuf, NNODES);
    k_aggregate<<<(NNODES * 32 + 255) / 256, 256, 0, stream>>>(hbuf, dinv, row_start,
                                                               csr_src, csr_w, b1, abuf);
    // layer 2
    k_gemm<<<(NNODES + 127) / 128, 256, 0, stream>>>(abuf, W2, hbuf, NNODES);
    k_aggregate<<<(NNODES * 32 + 255) / 256, 256, 0, stream>>>(hbuf, dinv, row_start,
                                                               csr_src, csr_w, b2, abuf);
    // pool + head
    k_pool1<<<NGRAPHS * PPG, 256, 0, stream>>>(abuf, batch, part);
    k_pool2<<<NGRAPHS, 128, 0, stream>>>(part, batch, gmean);
    k_head<<<1, 256, 0, stream>>>(gmean, fc1W, fc1b, gam, bet, fc3W, fc3b, out);
}

// Round 5
// 267.534 us; speedup vs baseline: 1.8124x; 1.2115x over previous
//
#include <hip/hip_runtime.h>

#define NNODES 50000
#define NEDGES 600000
#define NGRAPHS 64
#define BN_EPS 1e-5f
#define NB1 ((NNODES + 255) / 256)   // 196 node-blocks
#define PPG 16                        // pooling parts per graph
#define GEMM_BLOCKS ((NNODES + 127) / 128)   // 391
#define COUNT_BLOCKS 512

// ---------------- fp32 GEMM tile body: C[M,128] = A[M,128] @ W[128,128] ----------------
// 128x128 tile per block, 8x8 micro-tile per thread, k-chunks of 32.
// a_lds transposed [k][row] stride 132; w_lds col-swizzled (2-way max on b128 reads).

__device__ __forceinline__ void gemm_tile(const float* __restrict__ A,
        const float* __restrict__ W, float* __restrict__ C, int block) {
    __shared__ float a_lds[32][132];
    __shared__ float w_lds[32][192];
    const int tid = threadIdx.x;
    const int row0 = block * 128;
    const int tx = tid & 15;
    const int ty = tid >> 4;
    float acc[8][8];
#pragma unroll
    for (int i = 0; i < 8; ++i)
#pragma unroll
        for (int j = 0; j < 8; ++j) acc[i][j] = 0.f;

    for (int kc = 0; kc < 128; kc += 32) {
#pragma unroll
        for (int p = 0; p < 4; ++p) {
            int idx = p * 256 + tid;
            int r = idx >> 3;
            int k4 = (idx & 7) << 2;
            int grow = row0 + r;
            float4 v = make_float4(0.f, 0.f, 0.f, 0.f);
            if (grow < NNODES) v = *(const float4*)(A + (size_t)grow * 128 + kc + k4);
            a_lds[k4 + 0][r] = v.x; a_lds[k4 + 1][r] = v.y;
            a_lds[k4 + 2][r] = v.z; a_lds[k4 + 3][r] = v.w;
        }
#pragma unroll
        for (int p = 0; p < 4; ++p) {
            int idx = p * 256 + tid;
            int kk = idx >> 5;
            int c4 = idx & 31;
            float4 v = *(const float4*)(W + (size_t)(kc + kk) * 128 + c4 * 4);
            int sw = 12 * (c4 >> 1) + ((c4 & 1) << 2);
            *(float4*)&w_lds[kk][sw] = v;
        }
        __syncthreads();
#pragma unroll
        for (int k = 0; k < 32; ++k) {
            float a[8], b[8];
            *(float4*)&a[0] = *(const float4*)&a_lds[k][ty * 8];
            *(float4*)&a[4] = *(const float4*)&a_lds[k][ty * 8 + 4];
            *(float4*)&b[0] = *(const float4*)&w_lds[k][tx * 12];
            *(float4*)&b[4] = *(const float4*)&w_lds[k][tx * 12 + 4];
#pragma unroll
            for (int i = 0; i < 8; ++i)
#pragma unroll
                for (int j = 0; j < 8; ++j)
                    acc[i][j] = fmaf(a[i], b[j], acc[i][j]);
        }
        __syncthreads();
    }
#pragma unroll
    for (int i = 0; i < 8; ++i) {
        int grow = row0 + ty * 8 + i;
        if (grow < NNODES) {
            float4 v0 = make_float4(acc[i][0], acc[i][1], acc[i][2], acc[i][3]);
            float4 v1 = make_float4(acc[i][4], acc[i][5], acc[i][6], acc[i][7]);
            *(float4*)(C + (size_t)grow * 128 + tx * 8) = v0;
            *(float4*)(C + (size_t)grow * 128 + tx * 8 + 4) = v1;
        }
    }
}

// fused: GEMM1 blocks + edge-ticket histogram blocks (independent work, co-resident)
__global__ __launch_bounds__(256) void k_gemm1_count(const float* __restrict__ A,
        const float* __restrict__ W, float* __restrict__ C,
        const int* __restrict__ dst, int* __restrict__ cnt, int* __restrict__ rank) {
    if (blockIdx.x >= GEMM_BLOCKS) {
        int b = blockIdx.x - GEMM_BLOCKS;
        for (int e = b * 256 + threadIdx.x; e < NEDGES; e += COUNT_BLOCKS * 256) {
            int d = dst[e];
            rank[e] = atomicAdd(&cnt[d], 1);
        }
        return;
    }
    gemm_tile(A, W, C, blockIdx.x);
}

__global__ __launch_bounds__(256) void k_gemm(const float* __restrict__ A,
        const float* __restrict__ W, float* __restrict__ C) {
    gemm_tile(A, W, C, blockIdx.x);
}

// ---------------- scan (3-phase, over cnt -> row_start) ----------------

__global__ __launch_bounds__(256) void k_scan1(const int* __restrict__ cnt,
        int* __restrict__ excl, int* __restrict__ bsum) {
    __shared__ int sh[256];
    int b = blockIdx.x, t = threadIdx.x;
    int idx = b * 256 + t;
    int v = (idx < NNODES) ? cnt[idx] : 0;
    sh[t] = v;
    __syncthreads();
#pragma unroll
    for (int off = 1; off < 256; off <<= 1) {
        int x = (t >= off) ? sh[t - off] : 0;
        __syncthreads();
        sh[t] += x;
        __syncthreads();
    }
    if (idx < NNODES) excl[idx] = sh[t] - v;
    if (t == 255) bsum[b] = sh[255];
}

__global__ __launch_bounds__(256) void k_scan2(int* __restrict__ bsum) {
    __shared__ int sh[256];
    int t = threadIdx.x;
    int v = (t < NB1) ? bsum[t] : 0;
    sh[t] = v;
    __syncthreads();
#pragma unroll
    for (int off = 1; off < 256; off <<= 1) {
        int x = (t >= off) ? sh[t - off] : 0;
        __syncthreads();
        sh[t] += x;
        __syncthreads();
    }
    if (t < NB1) bsum[t] = sh[t] - v;
}

__global__ __launch_bounds__(256) void k_scan3(const int* __restrict__ excl,
        const int* __restrict__ bsum, int* __restrict__ row_start) {
    int b = blockIdx.x, t = threadIdx.x;
    int idx = b * 256 + t;
    if (idx < NNODES) row_start[idx] = excl[idx] + bsum[b];
    if (idx == 0) row_start[NNODES] = NEDGES;
}

// ---------------- atomic-free CSR fill (slot = row_start + precomputed rank) ----------

__global__ __launch_bounds__(256) void k_place(const int* __restrict__ src,
        const int* __restrict__ dst, const float* __restrict__ ew,
        const int* __restrict__ rank, const int* __restrict__ row_start,
        int2* __restrict__ csr_pk) {
    int e = blockIdx.x * 256 + threadIdx.x;
    if (e < NEDGES) {
        int d = dst[e];
        int slot = row_start[d] + rank[e];
        csr_pk[slot] = make_int2(src[e], __float_as_int(ew[e]));
    }
}

// deg[i] = 1 + sum(row ew)  ->  dinv[i] = rsqrt(deg)
__global__ __launch_bounds__(256) void k_deg(const int* __restrict__ row_start,
        const int2* __restrict__ csr_pk, float* __restrict__ dinv) {
    int i = blockIdx.x * 256 + threadIdx.x;
    if (i >= NNODES) return;
    int e0 = row_start[i], e1 = row_start[i + 1];
    float deg = 1.f;
    for (int e = e0; e < e1; ++e) deg += __int_as_float(csr_pk[e].y);
    dinv[i] = rsqrtf(deg);
}

// overwrite packed ew with final norm weight dinv[s]*ew*dinv[i]
__global__ __launch_bounds__(256) void k_wfill(const int* __restrict__ row_start,
        int2* __restrict__ csr_pk, const float* __restrict__ dinv) {
    int i = blockIdx.x * 256 + threadIdx.x;
    if (i >= NNODES) return;
    int e0 = row_start[i], e1 = row_start[i + 1];
    float di = dinv[i];
    for (int e = e0; e < e1; ++e) {
        int2 pk = csr_pk[e];
        float w = dinv[pk.x] * __int_as_float(pk.y) * di;
        csr_pk[e].y = __float_as_int(w);
    }
}

// ---------------- GCN aggregate: out = relu(A_hat @ h + bias) ----------------
// 32 lanes per node, float4 per lane (128 ch); 4-edge unrolled gather.

__global__ __launch_bounds__(256) void k_aggregate(const float* __restrict__ h,
        const float* __restrict__ dinv, const int* __restrict__ row_start,
        const int2* __restrict__ csr_pk, const float* __restrict__ bias,
        float* __restrict__ out) {
    int gtid = blockIdx.x * 256 + threadIdx.x;
    int i = gtid >> 5;
    int lane = (gtid & 31) << 2;
    if (i >= NNODES) return;
    float di = dinv[i];
    float sw = di * di;
    float4 hv = *(const float4*)(h + (size_t)i * 128 + lane);
    float ax = sw * hv.x, ay = sw * hv.y, az = sw * hv.z, aw = sw * hv.w;
    int e = row_start[i];
    int e1 = row_start[i + 1];
    for (; e + 3 < e1; e += 4) {
        int2 p0 = csr_pk[e], p1 = csr_pk[e + 1], p2 = csr_pk[e + 2], p3 = csr_pk[e + 3];
        float4 v0 = *(const float4*)(h + (size_t)p0.x * 128 + lane);
        float4 v1 = *(const float4*)(h + (size_t)p1.x * 128 + lane);
        float4 v2 = *(const float4*)(h + (size_t)p2.x * 128 + lane);
        float4 v3 = *(const float4*)(h + (size_t)p3.x * 128 + lane);
        float w0 = __int_as_float(p0.y), w1 = __int_as_float(p1.y);
        float w2 = __int_as_float(p2.y), w3 = __int_as_float(p3.y);
        ax = fmaf(w0, v0.x, ax); ay = fmaf(w0, v0.y, ay);
        az = fmaf(w0, v0.z, az); aw = fmaf(w0, v0.w, aw);
        ax = fmaf(w1, v1.x, ax); ay = fmaf(w1, v1.y, ay);
        az = fmaf(w1, v1.z, az); aw = fmaf(w1, v1.w, aw);
        ax = fmaf(w2, v2.x, ax); ay = fmaf(w2, v2.y, ay);
        az = fmaf(w2, v2.z, az); aw = fmaf(w2, v2.w, aw);
        ax = fmaf(w3, v3.x, ax); ay = fmaf(w3, v3.y, ay);
        az = fmaf(w3, v3.z, az); aw = fmaf(w3, v3.w, aw);
    }
    for (; e < e1; ++e) {
        int2 p0 = csr_pk[e];
        float w0 = __int_as_float(p0.y);
        float4 v0 = *(const float4*)(h + (size_t)p0.x * 128 + lane);
        ax = fmaf(w0, v0.x, ax); ay = fmaf(w0, v0.y, ay);
        az = fmaf(w0, v0.z, az); aw = fmaf(w0, v0.w, aw);
    }
    float4 b = *(const float4*)(bias + lane);
    float4 o;
    o.x = fmaxf(ax + b.x, 0.f);
    o.y = fmaxf(ay + b.y, 0.f);
    o.z = fmaxf(az + b.z, 0.f);
    o.w = fmaxf(aw + b.w, 0.f);
    *(float4*)(out + (size_t)i * 128 + lane) = o;
}

// ---------------- pooling: 2-phase deterministic partial sums ----------------

__global__ __launch_bounds__(256) void k_pool1(const float* __restrict__ h2,
        const int* __restrict__ batch, float* __restrict__ part) {
    __shared__ float sh[256];
    int g = blockIdx.x / PPG;
    int p = blockIdx.x % PPG;
    int t = threadIdx.x;
    int lo = 0, hi = NNODES;
    while (lo < hi) { int mid = (lo + hi) >> 1; if (batch[mid] < g) lo = mid + 1; else hi = mid; }
    int b0 = lo;
    lo = 0; hi = NNODES;
    int g1 = g + 1;
    while (lo < hi) { int mid = (lo + hi) >> 1; if (batch[mid] < g1) lo = mid + 1; else hi = mid; }
    int b1 = lo;

    int c = t & 127, q = t >> 7;
    float acc = 0.f;
    for (int r = b0 + p * 2 + q; r < b1; r += PPG * 2) acc += h2[(size_t)r * 128 + c];
    sh[t] = acc;
    __syncthreads();
    if (t < 128) part[((size_t)g * PPG + p) * 128 + t] = sh[t] + sh[t + 128];
}

__global__ __launch_bounds__(128) void k_pool2(const float* __restrict__ part,
        const int* __restrict__ batch, float* __restrict__ gmean) {
    int g = blockIdx.x;
    int t = threadIdx.x;
    int lo = 0, hi = NNODES;
    while (lo < hi) { int mid = (lo + hi) >> 1; if (batch[mid] < g) lo = mid + 1; else hi = mid; }
    int b0 = lo;
    lo = 0; hi = NNODES;
    int g1 = g + 1;
    while (lo < hi) { int mid = (lo + hi) >> 1; if (batch[mid] < g1) lo = mid + 1; else hi = mid; }
    int b1 = lo;
    float s = 0.f;
#pragma unroll
    for (int p = 0; p < PPG; ++p) s += part[((size_t)g * PPG + p) * 128 + t];
    float n = (float)(b1 - b0);
    gmean[g * 128 + t] = s / fmaxf(n, 1.f);
}

// ---------------- head: z = relu(g@fc1+b); BN(train-mode); out = z@fc3+b ----

__global__ __launch_bounds__(256) void k_head(const float* __restrict__ gmean,
        const float* __restrict__ fc1W, const float* __restrict__ fc1b,
        const float* __restrict__ gamma, const float* __restrict__ beta,
        const float* __restrict__ fc3W, const float* __restrict__ fc3b,
        float* __restrict__ out) {
    __shared__ float z[64][65];
    __shared__ float mu[64], isd[64];
    int t = threadIdx.x;
    int r = t >> 2;
    int c0 = (t & 3) * 16;
    float acc[16];
#pragma unroll
    for (int j = 0; j < 16; ++j) acc[j] = 0.f;
    for (int k = 0; k < 128; ++k) {
        float gv = gmean[r * 128 + k];
#pragma unroll
        for (int j = 0; j < 16; ++j) acc[j] = fmaf(gv, fc1W[k * 64 + c0 + j], acc[j]);
    }
#pragma unroll
    for (int j = 0; j < 16; ++j)
        z[r][c0 + j] = fmaxf(acc[j] + fc1b[c0 + j], 0.f);
    __syncthreads();
    if (t < 64) {
        float m = 0.f;
        for (int rr = 0; rr < 64; ++rr) m += z[rr][t];
        m *= (1.f / 64.f);
        float v = 0.f;
        for (int rr = 0; rr < 64; ++rr) { float d = z[rr][t] - m; v = fmaf(d, d, v); }
        v *= (1.f / 64.f);
        mu[t] = m;
        isd[t] = rsqrtf(v + BN_EPS);
    }
    __syncthreads();
    if (t < 64) {
        float a2 = fc3b[0];
        for (int cc = 0; cc < 64; ++cc) {
            float zn = fmaf(gamma[cc] * (z[t][cc] - mu[cc]), isd[cc], beta[cc]);
            a2 = fmaf(zn, fc3W[cc], a2);
        }
        out[t] = a2;
    }
}

// ---------------- launch ----------------

extern "C" void kernel_launch(void* const* d_in, const int* in_sizes, int n_in,
                              void* d_out, int out_size, void* d_ws, size_t ws_size,
                              hipStream_t stream) {
    const float* x    = (const float*)d_in[0];
    const int*   ei   = (const int*)d_in[1];
    const int*   batch= (const int*)d_in[2];
    const float* ew   = (const float*)d_in[3];
    const float* W1   = (const float*)d_in[4];
    const float* b1   = (const float*)d_in[5];
    const float* W2   = (const float*)d_in[6];
    const float* b2   = (const float*)d_in[7];
    const float* fc1W = (const float*)d_in[8];
    const float* fc1b = (const float*)d_in[9];
    const float* gam  = (const float*)d_in[10];
    const float* bet  = (const float*)d_in[11];
    const float* fc3W = (const float*)d_in[12];
    const float* fc3b = (const float*)d_in[13];
    float* out = (float*)d_out;
    const int* srcp = ei;
    const int* dstp = ei + NEDGES;

    char* wsb = (char*)d_ws;
    size_t off = 0;
    auto alloc = [&](size_t bytes) {
        void* p = wsb + off;
        off = (off + bytes + 255) & ~(size_t)255;
        return p;
    };
    float* dinv      = (float*)alloc(NNODES * 4);
    int*   row_start = (int*)alloc((NNODES + 1) * 4);
    int*   cnt       = (int*)alloc(NNODES * 4);
    int*   excl      = (int*)alloc(NNODES * 4);
    int*   bsum      = (int*)alloc(NB1 * 4);
    int*   rank      = (int*)alloc((size_t)NEDGES * 4);
    int2*  csr_pk    = (int2*)alloc((size_t)NEDGES * 8);
    float* hbuf      = (float*)alloc((size_t)NNODES * 128 * 4);
    float* abuf      = (float*)alloc((size_t)NNODES * 128 * 4);
    float* part      = (float*)alloc((size_t)NGRAPHS * PPG * 128 * 4);
    float* gmean     = (float*)alloc(NGRAPHS * 128 * 4);
    (void)ws_size; (void)in_sizes; (void)n_in; (void)out_size;

    const int nb_edges = (NEDGES + 255) / 256;

    hipMemsetAsync(cnt, 0, NNODES * 4, stream);
    // layer-1 GEMM fused with edge ticketing (independent work, overlapped)
    k_gemm1_count<<<GEMM_BLOCKS + COUNT_BLOCKS, 256, 0, stream>>>(x, W1, hbuf, dstp, cnt, rank);
    k_scan1<<<NB1, 256, 0, stream>>>(cnt, excl, bsum);
    k_scan2<<<1, 256, 0, stream>>>(bsum);
    k_scan3<<<NB1, 256, 0, stream>>>(excl, bsum, row_start);
    k_place<<<nb_edges, 256, 0, stream>>>(srcp, dstp, ew, rank, row_start, csr_pk);
    k_deg<<<NB1, 256, 0, stream>>>(row_start, csr_pk, dinv);
    k_wfill<<<NB1, 256, 0, stream>>>(row_start, csr_pk, dinv);

    // layer 1 aggregate
    k_aggregate<<<(NNODES * 32 + 255) / 256, 256, 0, stream>>>(hbuf, dinv, row_start,
                                                               csr_pk, b1, abuf);
    // layer 2
    k_gemm<<<GEMM_BLOCKS, 256, 0, stream>>>(abuf, W2, hbuf);
    k_aggregate<<<(NNODES * 32 + 255) / 256, 256, 0, stream>>>(hbuf, dinv, row_start,
                                                               csr_pk, b2, abuf);
    // pool + head
    k_pool1<<<NGRAPHS * PPG, 256, 0, stream>>>(abuf, batch, part);
    k_pool2<<<NGRAPHS, 128, 0, stream>>>(part, batch, gmean);
    k_head<<<1, 256, 0, stream>>>(gmean, fc1W, fc1b, gam, bet, fc3W, fc3b, out);
}